// Round 1
// baseline (534.485 us; speedup 1.0000x reference)
//
#include <hip/hip_runtime.h>
#include <hip/hip_bf16.h>

// PixelContrastLossOnlyNeg on MI355X.
// feats [16,256,128,128] f32, queue [256,256] f32, labels [262144,256] i32 -> scalar f32.
// Fused bf16-MFMA GEMM (N=262144, M=256, K=256) + masked-exp reduction.
// Memory floor: feats 256MB + labels 256MB = 512MB -> ~81us @ 6.3TB/s.

typedef __bf16 bf16x8 __attribute__((ext_vector_type(8)));
typedef float floatx4 __attribute__((ext_vector_type(4)));

using gl_void = const __attribute__((address_space(1))) void;
using lds_void = __attribute__((address_space(3))) void;

union BFrag {
  unsigned int u32[4];
  bf16x8 bf;
};

// Pack two f32 -> two bf16 (round-half-up; bias ~2^-17 rel, irrelevant here). 5 VALU ops.
__device__ __forceinline__ unsigned int pack_bf2(float a, float b) {
  unsigned int ua = __float_as_uint(a) + 0x8000u;
  unsigned int ub = __float_as_uint(b) + 0x8000u;
  return (ua >> 16) | (ub & 0xffff0000u);
}

// ---------------------------------------------------------------------------
// k0: queue f32 -> bf16 * (1/T), stored pre-swizzled in A-fragment lane order:
//   tile t = m16*8 + ks  (m16 = m>>4, ks = k>>5), within tile: lane L holds
//   A[m = m16*16 + (L&15)][k = ks*32 + (L>>4)*8 + j], j=0..7 -> 16B at (t*64+L)*16.
// Main kernel A-frag load is then one perfectly-coalesced dwordx4 per (tile,lane).
// Also zeroes the global accumulators (sum, cnt).
// ---------------------------------------------------------------------------
__global__ void qprep(const float* __restrict__ queue,
                      unsigned short* __restrict__ qs,
                      float* __restrict__ accum) {
  const int gt = blockIdx.x * 256 + threadIdx.x;  // 0..8191
  const int t = gt >> 6;
  const int lane = gt & 63;
  const int m = ((t >> 3) << 4) | (lane & 15);
  const int k0 = ((t & 7) << 5) | ((lane >> 4) << 3);
  const float* qr = queue + m * 256 + k0;
  const float TINV = 14.2857142857142857f;  // 1/0.07 folded into Q
  BFrag u;
#pragma unroll
  for (int j = 0; j < 4; ++j)
    u.u32[j] = pack_bf2(qr[2 * j] * TINV, qr[2 * j + 1] * TINV);
  *(uint4*)(qs + (size_t)gt * 8) = *(const uint4*)u.u32;
  if (gt == 0) { accum[0] = 0.0f; accum[1] = 0.0f; }
}

// ---------------------------------------------------------------------------
// k1: main fused kernel. Block = 64 pixels x 256 classes, 256 threads (4 waves),
// wave w owns M rows [64w, 64w+64). Grid = 16 batches * 256 tiles = 4096 blocks.
// ---------------------------------------------------------------------------
__global__ __launch_bounds__(256, 2) void pcl_main(
    const float* __restrict__ feats,
    const int* __restrict__ labels,
    const unsigned short* __restrict__ qs,
    float* __restrict__ accum) {
  // F tile, natural [k][n] fp32 layout, 16B pad per 4-row group:
  // elem(k,n) at (k>>2)*260 + (k&3)*64 + n  (group stride 1040B keeps
  // global_load_lds lane-contiguity AND makes B-frag ds_read_b32 2-way only).
  __shared__ float Fl[16640];        // 66,560 B
  __shared__ float Red[8][64];       // per-wave neg/pos partials

  const int bx = blockIdx.x;
  const int bidx = bx >> 8;          // batch
  const int hw0 = (bx & 255) << 6;   // pixel tile base within batch
  const int tid = threadIdx.x;
  const int w = tid >> 6;
  const int lane = tid & 63;
  const int qd = lane >> 4;          // quad 0..3
  const int s = lane & 15;

  // ---- stage F tile: 64KB fp32, async global->LDS, 16 wave-instrs per wave ----
  {
    const float* gbase = feats + (size_t)bidx * 256 * 16384 + hw0;
#pragma unroll
    for (int i = 0; i < 16; ++i) {
      const int g = (w << 4) + i;                         // 4-row group 0..63
      const float* gp = gbase + (size_t)((g << 2) + qd) * 16384 + (s << 2);
      float* lp = &Fl[g * 260];                           // wave-uniform base
      __builtin_amdgcn_global_load_lds((gl_void*)gp, (lds_void*)lp, 16, 0, 0);
    }
  }

  floatx4 acc[4][4];
#pragma unroll
  for (int mt = 0; mt < 4; ++mt)
#pragma unroll
    for (int nt = 0; nt < 4; ++nt)
      acc[mt][nt] = floatx4{0.0f, 0.0f, 0.0f, 0.0f};

  __syncthreads();  // compiler emits vmcnt(0) drain for global_load_lds

  // ---- K loop: 8 steps of 32, 16 MFMAs each ----
  const bf16x8* qfrag = (const bf16x8*)qs;
#pragma unroll
  for (int ks = 0; ks < 8; ++ks) {
    bf16x8 af[4];
#pragma unroll
    for (int mt = 0; mt < 4; ++mt) {
      const int t = ((((w << 2) + mt) << 3) | ks);
      af[mt] = qfrag[t * 64 + lane];  // coalesced 1KB, L2-hot
    }
    bf16x8 bfv[4];
#pragma unroll
    for (int nt = 0; nt < 4; ++nt) {
      // lane needs F[k = 32ks + 8qd + j][n = 16nt + s], j=0..7
      const float* bp = &Fl[((ks << 3) + (qd << 1)) * 260 + (nt << 4) + s];
      BFrag u;
      u.u32[0] = pack_bf2(bp[0], bp[64]);
      u.u32[1] = pack_bf2(bp[128], bp[192]);
      u.u32[2] = pack_bf2(bp[260], bp[324]);
      u.u32[3] = pack_bf2(bp[388], bp[452]);
      bfv[nt] = u.bf;
    }
#pragma unroll
    for (int mt = 0; mt < 4; ++mt)
#pragma unroll
      for (int nt = 0; nt < 4; ++nt)
        acc[mt][nt] = __builtin_amdgcn_mfma_f32_16x16x32_bf16(af[mt], bfv[nt],
                                                              acc[mt][nt], 0, 0, 0);
  }

  // ---- epilogue: lane holds C[m = 64w+16mt+4qd+r][n = 16nt+s] ----
  // labels int4 at [pixel][64w+16mt+4qd .. +3] matches the 4 acc regs exactly.
  const size_t nbase = (size_t)bx << 6;  // global pixel base (= bidx*16384 + hw0)
  int4 lab[4][4];
#pragma unroll
  for (int mt = 0; mt < 4; ++mt)
#pragma unroll
    for (int nt = 0; nt < 4; ++nt)
      lab[mt][nt] = *(const int4*)(labels + ((nbase + (nt << 4) + s) << 8) +
                                   (w << 6) + (mt << 4) + (qd << 2));

  float nn[4] = {0.f, 0.f, 0.f, 0.f};  // sum_neg partials per nt
  float pp[4] = {0.f, 0.f, 0.f, 0.f};  // sum_pos partials per nt
#define ACCUM_TERM(LV, AV)                          \
  do {                                              \
    const float fl_ = (float)(LV);                  \
    const float l_ = (AV);                          \
    const float e_ = __expf(l_);                    \
    const float en_ = __expf(-l_);                  \
    nn[nt] += (1.0f - fl_) * e_;                    \
    pp[nt] += fl_ * en_;                            \
  } while (0)

#pragma unroll
  for (int mt = 0; mt < 4; ++mt) {
#pragma unroll
    for (int nt = 0; nt < 4; ++nt) {
      const int4 lb = lab[mt][nt];
      const floatx4 a = acc[mt][nt];
      ACCUM_TERM(lb.x, a[0]);
      ACCUM_TERM(lb.y, a[1]);
      ACCUM_TERM(lb.z, a[2]);
      ACCUM_TERM(lb.w, a[3]);
    }
  }
#undef ACCUM_TERM

  // quad-reduce (lanes l, l+16, l+32, l+48 share a pixel)
#pragma unroll
  for (int nt = 0; nt < 4; ++nt) {
    nn[nt] += __shfl_xor(nn[nt], 16);
    nn[nt] += __shfl_xor(nn[nt], 32);
    pp[nt] += __shfl_xor(pp[nt], 16);
    pp[nt] += __shfl_xor(pp[nt], 32);
  }
  if (lane < 16) {
#pragma unroll
    for (int nt = 0; nt < 4; ++nt) {
      Red[(w << 1) | 0][(nt << 4) + lane] = nn[nt];
      Red[(w << 1) | 1][(nt << 4) + lane] = pp[nt];
    }
  }
  __syncthreads();

  if (tid < 64) {
    const float sn = Red[0][tid] + Red[2][tid] + Red[4][tid] + Red[6][tid];
    const float sp = Red[1][tid] + Red[3][tid] + Red[5][tid] + Red[7][tid];
    float loss = logf(sn * sp + 1.0f);
    float c = (loss != 0.0f) ? 1.0f : 0.0f;
#pragma unroll
    for (int off = 32; off > 0; off >>= 1) {
      loss += __shfl_xor(loss, off);
      c += __shfl_xor(c, off);
    }
    if (tid == 0) {
      atomicAdd(&accum[0], loss);
      atomicAdd(&accum[1], c);
    }
  }
}

// ---------------------------------------------------------------------------
// k2: scalar finalize. Mirrors where(lb_num==0, 0, sum/max(lb_num,1)).
// ---------------------------------------------------------------------------
__global__ void pcl_finalize(const float* __restrict__ accum,
                             float* __restrict__ out) {
  const float ssum = accum[0];
  const float c = accum[1];
  out[0] = (c != 0.0f) ? (ssum / c) : 0.0f;
}

extern "C" void kernel_launch(void* const* d_in, const int* in_sizes, int n_in,
                              void* d_out, int out_size, void* d_ws, size_t ws_size,
                              hipStream_t stream) {
  (void)in_sizes; (void)n_in; (void)out_size; (void)ws_size;
  const float* feats = (const float*)d_in[0];
  const float* queue = (const float*)d_in[1];
  const int* labels = (const int*)d_in[2];

  // workspace: [0,128KB) swizzled bf16 queue, [128KB, 128KB+8B) accumulators
  unsigned short* qs = (unsigned short*)d_ws;
  float* accum = (float*)((char*)d_ws + 256 * 256 * sizeof(unsigned short));

  qprep<<<32, 256, 0, stream>>>(queue, qs, accum);
  pcl_main<<<4096, 256, 0, stream>>>(feats, labels, qs, accum);
  pcl_finalize<<<1, 1, 0, stream>>>(accum, (float*)d_out);
}